// Round 8
// baseline (115.298 us; speedup 1.0000x reference)
//
#include <hip/hip_runtime.h>

namespace {

constexpr int NCOL  = 3;
constexpr int N_IN  = 4;
constexpr int N_OUT = 8;
constexpr int T_W   = 37;
constexpr int NB    = 4;
constexpr int NX    = 16384;
constexpr int MAT   = 18;                  // floats per complex 3x3
constexpr int SITES = NB * NX;             // 65536
constexpr int NTHREADS = SITES * 3 * 8;    // (site,j) x (axis a, half g) = 1,572,864
constexpr int OUT_U = SITES * 4 * MAT;     // floats of output-0 (u passthrough)

// W matrices: base (bs*4+v)*72B -> 16B-parity = v&1 (compile-time in unrolled loop)
template<int PAR>
__device__ __forceinline__ void load_mat18(const float* __restrict__ p, float* M) {
    if constexpr (PAR == 0) {
        float4 q0 = *(const float4*)(p + 0);
        float4 q1 = *(const float4*)(p + 4);
        float4 q2 = *(const float4*)(p + 8);
        float4 q3 = *(const float4*)(p + 12);
        float2 q4 = *(const float2*)(p + 16);
        M[0]=q0.x;  M[1]=q0.y;  M[2]=q0.z;  M[3]=q0.w;
        M[4]=q1.x;  M[5]=q1.y;  M[6]=q1.z;  M[7]=q1.w;
        M[8]=q2.x;  M[9]=q2.y;  M[10]=q2.z; M[11]=q2.w;
        M[12]=q3.x; M[13]=q3.y; M[14]=q3.z; M[15]=q3.w;
        M[16]=q4.x; M[17]=q4.y;
    } else {
        float2 q4 = *(const float2*)(p + 0);
        float4 q0 = *(const float4*)(p + 2);
        float4 q1 = *(const float4*)(p + 6);
        float4 q2 = *(const float4*)(p + 10);
        float4 q3 = *(const float4*)(p + 14);
        M[0]=q4.x;  M[1]=q4.y;
        M[2]=q0.x;  M[3]=q0.y;  M[4]=q0.z;  M[5]=q0.w;
        M[6]=q1.x;  M[7]=q1.y;  M[8]=q1.z;  M[9]=q1.w;
        M[10]=q2.x; M[11]=q2.y; M[12]=q2.z; M[13]=q2.w;
        M[14]=q3.x; M[15]=q3.y; M[16]=q3.z; M[17]=q3.w;
    }
}

// U matrices: base (bs*4+a)*72B with runtime a -> parity unknown, use 8B loads
__device__ __forceinline__ void load9f2(const float* __restrict__ p, float* M) {
#pragma unroll
    for (int k = 0; k < 9; ++k) {
        float2 e = *(const float2*)(p + 2 * k);
        M[2 * k]     = e.x;
        M[2 * k + 1] = e.y;
    }
}

__global__ __launch_bounds__(256) void copy_kernel(
    const float4* __restrict__ u4, float4* __restrict__ o4)
{
    const int gid = blockIdx.x * 256 + threadIdx.x;
#pragma unroll
    for (int k = 0; k < 4; ++k) {
        int idx = gid + k * (OUT_U / 16);
        o4[idx] = u4[idx];
    }
}

__global__ __launch_bounds__(256) void lconv_kernel(
    const float* __restrict__ u,
    const float* __restrict__ w,
    const float* __restrict__ wgt,
    float* __restrict__ out)
{
    __shared__ float wT[T_W][N_OUT];   // wT[v][uo] = wgt[uo*37+v]
    const int tid = threadIdx.x;
    for (int idx = tid; idx < T_W * N_OUT; idx += 256) {
        wT[idx >> 3][idx & 7] = wgt[(idx & 7) * T_W + (idx >> 3)];
    }
    __syncthreads();

    const int gid = blockIdx.x * 256 + tid;
    const int a   = tid & 3;          // axis (per-lane; addresses only)
    const int g   = (tid >> 2) & 1;   // output half (per-lane; addresses only)
    const int sjg = gid >> 3;         // (site, j)
    const int j   = sjg % 3;
    const int bs  = sjg / 3;
    const int x   = bs & (NX - 1);

    // axis geometry: dims (8,8,16,16), strides 2^{11,8,4,0}
    const int sh    = (a == 0) ? 11 : (a == 1) ? 8 : (a == 2) ? 4 : 0;
    const int dmask = (a < 2) ? 7 : 15;
    const int ca    = (x >> sh) & dmask;
    const int xp    = (ca == dmask) ? x - (dmask << sh) : x + (1 << sh);
    const int xm    = (ca == 0)     ? x + (dmask << sh) : x - (1 << sh);
    const int bsp   = bs - x + xp;
    const int bsm   = bs - x + xm;

    float acc[4][NCOL][2];
#pragma unroll
    for (int t = 0; t < 4; ++t)
#pragma unroll
        for (int i = 0; i < NCOL; ++i) { acc[t][i][0] = 0.f; acc[t][i][1] = 0.f; }

    // ---- term 0: this thread handles v = a, outputs [4g, 4g+4) ----
    {
        const float* __restrict__ wb = w + (size_t)(bs * 4 + a) * MAT;
        float4 cw4 = *(const float4*)&wT[a][4 * g];        // runtime LDS addr: fine
        const float cw[4] = {cw4.x, cw4.y, cw4.z, cw4.w};
#pragma unroll
        for (int i = 0; i < NCOL; ++i) {
            float2 e = *(const float2*)(wb + (i * NCOL + j) * 2);
#pragma unroll
            for (int t = 0; t < 4; ++t) {
                acc[t][i][0] = fmaf(cw[t], e.x, acc[t][i][0]);
                acc[t][i][1] = fmaf(cw[t], e.y, acc[t][i][1]);
            }
        }
    }

    // ---- orientation +1: U = u(x,a); neighbor w at bsp ----
    {
        const float* __restrict__ Up = u + (size_t)(bs * 4 + a) * MAT;
        float U[MAT];
        load9f2(Up, U);
        float vr[3], vi[3];                      // d+ = conj(row j of U)
#pragma unroll
        for (int k = 0; k < 3; ++k) {
            float2 e = *(const float2*)(Up + (j * NCOL + k) * 2);
            vr[k] = e.x;  vi[k] = -e.y;
        }
        const float* __restrict__ wn = w + (size_t)bsp * (N_IN * MAT);
#pragma unroll
        for (int v = 0; v < N_IN; ++v) {
            float W[MAT];
            if ((v & 1) == 0) load_mat18<0>(wn + v * MAT, W);
            else              load_mat18<1>(wn + v * MAT, W);

            float yr[3], yi[3];
#pragma unroll
            for (int i = 0; i < NCOL; ++i) {
                float sr = 0.f, si = 0.f;
#pragma unroll
                for (int k = 0; k < NCOL; ++k) {
                    float wr = W[(i*3+k)*2], wi = W[(i*3+k)*2+1];
                    sr = fmaf(wr, vr[k], sr); sr = fmaf(-wi, vi[k], sr);
                    si = fmaf(wr, vi[k], si); si = fmaf(wi, vr[k], si);
                }
                yr[i] = sr; yi[i] = si;
            }
            float cr[3], ci[3];                  // c+ = U * y (rows)
#pragma unroll
            for (int i = 0; i < NCOL; ++i) {
                float sr = 0.f, si = 0.f;
#pragma unroll
                for (int k = 0; k < NCOL; ++k) {
                    float ur = U[(i*3+k)*2], ui = U[(i*3+k)*2+1];
                    sr = fmaf(ur, yr[k], sr); sr = fmaf(-ui, yi[k], sr);
                    si = fmaf(ur, yi[k], si); si = fmaf(ui, yr[k], si);
                }
                cr[i] = sr; ci[i] = si;
            }
            float4 cw4 = *(const float4*)&wT[(1 + a) * 4 + v][4 * g];
            const float cw[4] = {cw4.x, cw4.y, cw4.z, cw4.w};
#pragma unroll
            for (int t = 0; t < 4; ++t)
#pragma unroll
                for (int i = 0; i < NCOL; ++i) {
                    acc[t][i][0] = fmaf(cw[t], cr[i], acc[t][i][0]);
                    acc[t][i][1] = fmaf(cw[t], ci[i], acc[t][i][1]);
                }
        }
    }

    // ---- orientation -1: U = u(x-e_a,a); neighbor w at bsm ----
    {
        const float* __restrict__ Um = u + (size_t)(bsm * 4 + a) * MAT;
        float U[MAT];
        load9f2(Um, U);
        float vr[3], vi[3];                      // d- = column j of U (no conj)
#pragma unroll
        for (int k = 0; k < 3; ++k) {
            float2 e = *(const float2*)(Um + (k * NCOL + j) * 2);
            vr[k] = e.x;  vi[k] = e.y;
        }
        const float* __restrict__ wn = w + (size_t)bsm * (N_IN * MAT);
#pragma unroll
        for (int v = 0; v < N_IN; ++v) {
            float W[MAT];
            if ((v & 1) == 0) load_mat18<0>(wn + v * MAT, W);
            else              load_mat18<1>(wn + v * MAT, W);

            float yr[3], yi[3];
#pragma unroll
            for (int i = 0; i < NCOL; ++i) {
                float sr = 0.f, si = 0.f;
#pragma unroll
                for (int k = 0; k < NCOL; ++k) {
                    float wr = W[(i*3+k)*2], wi = W[(i*3+k)*2+1];
                    sr = fmaf(wr, vr[k], sr); sr = fmaf(-wi, vi[k], sr);
                    si = fmaf(wr, vi[k], si); si = fmaf(wi, vr[k], si);
                }
                yr[i] = sr; yi[i] = si;
            }
            float cr[3], ci[3];                  // c- = U^H * y (conj columns)
#pragma unroll
            for (int i = 0; i < NCOL; ++i) {
                float sr = 0.f, si = 0.f;
#pragma unroll
                for (int k = 0; k < NCOL; ++k) {
                    float ur = U[(k*3+i)*2], ui = U[(k*3+i)*2+1];
                    sr = fmaf(ur, yr[k], sr); sr = fmaf(ui, yi[k], sr);
                    si = fmaf(ur, yi[k], si); si = fmaf(-ui, yr[k], si);
                }
                cr[i] = sr; ci[i] = si;
            }
            float4 cw4 = *(const float4*)&wT[(5 + a) * 4 + v][4 * g];
            const float cw[4] = {cw4.x, cw4.y, cw4.z, cw4.w};
#pragma unroll
            for (int t = 0; t < 4; ++t)
#pragma unroll
                for (int i = 0; i < NCOL; ++i) {
                    acc[t][i][0] = fmaf(cw[t], cr[i], acc[t][i][0]);
                    acc[t][i][1] = fmaf(cw[t], ci[i], acc[t][i][1]);
                }
        }
    }

    // ---- butterfly reduce across the 4 axis-lanes (bits 0-1 of tid) ----
#pragma unroll
    for (int t = 0; t < 4; ++t)
#pragma unroll
        for (int i = 0; i < NCOL; ++i)
#pragma unroll
            for (int c = 0; c < 2; ++c) {
                float s = acc[t][i][c];
                s += __shfl_xor(s, 1);
                s += __shfl_xor(s, 2);
                acc[t][i][c] = s;
            }

    // ---- store: only a==0 lanes; thread writes channels [4g, 4g+4) ----
    if ((tid & 3) == 0) {
        float4 idq = *(const float4*)&wT[36][4 * g];
        const float cid[4] = {idq.x, idq.y, idq.z, idq.w};
        float* __restrict__ obase = out + (size_t)OUT_U + (size_t)bs * (N_OUT * MAT);
#pragma unroll
        for (int t = 0; t < 4; ++t)
#pragma unroll
            for (int i = 0; i < NCOL; ++i) {
                float2 e;
                e.x = acc[t][i][0] + ((i == j) ? cid[t] : 0.f);
                e.y = acc[t][i][1];
                *(float2*)(obase + (4 * g + t) * MAT + (i * NCOL + j) * 2) = e;
            }
    }
}

} // namespace

extern "C" void kernel_launch(void* const* d_in, const int* in_sizes, int n_in,
                              void* d_out, int out_size, void* d_ws, size_t ws_size,
                              hipStream_t stream)
{
    const float* u   = (const float*)d_in[0];
    const float* w   = (const float*)d_in[1];
    const float* wgt = (const float*)d_in[2];
    float* out = (float*)d_out;

    // u passthrough: OUT_U/4 float4; 1152 blocks * 256 thr * 4 f4 = exact
    copy_kernel<<<dim3(OUT_U / 16 / 256), dim3(256), 0, stream>>>(
        (const float4*)u, (float4*)out);

    lconv_kernel<<<dim3(NTHREADS / 256), dim3(256), 0, stream>>>(u, w, wgt, out);
}

// Round 9
// 66.619 us; speedup vs baseline: 1.7307x; 1.7307x over previous
//
#include <hip/hip_runtime.h>

namespace {

constexpr int NCOL  = 3;
constexpr int N_IN  = 4;
constexpr int N_OUT = 8;
constexpr int T_W   = 37;
constexpr int NB    = 4;
constexpr int NX    = 16384;
constexpr int MAT   = 18;                 // floats per complex 3x3
constexpr int SITES = NB * NX;            // 65536
constexpr int NTHREADS = SITES * 3 * 4;   // (site, j, axis a) = 786,432
constexpr int OUT_U = SITES * 4 * MAT;    // floats of output-0 (u passthrough)
constexpr int SLICE = 26;                 // padded floats per exchange slot (24 used)
constexpr int COPY_BLOCKS = 1536;         // blocks 0..1535 copy 3 float4 each (exact)

// W matrices: base (bs*4+v)*72B -> 16B-parity = v&1 (compile-time under unroll)
template<int PAR>
__device__ __forceinline__ void load_mat18(const float* __restrict__ p, float* M) {
    if constexpr (PAR == 0) {
        float4 q0 = *(const float4*)(p + 0);
        float4 q1 = *(const float4*)(p + 4);
        float4 q2 = *(const float4*)(p + 8);
        float4 q3 = *(const float4*)(p + 12);
        float2 q4 = *(const float2*)(p + 16);
        M[0]=q0.x;  M[1]=q0.y;  M[2]=q0.z;  M[3]=q0.w;
        M[4]=q1.x;  M[5]=q1.y;  M[6]=q1.z;  M[7]=q1.w;
        M[8]=q2.x;  M[9]=q2.y;  M[10]=q2.z; M[11]=q2.w;
        M[12]=q3.x; M[13]=q3.y; M[14]=q3.z; M[15]=q3.w;
        M[16]=q4.x; M[17]=q4.y;
    } else {
        float2 q4 = *(const float2*)(p + 0);
        float4 q0 = *(const float4*)(p + 2);
        float4 q1 = *(const float4*)(p + 6);
        float4 q2 = *(const float4*)(p + 10);
        float4 q3 = *(const float4*)(p + 14);
        M[0]=q4.x;  M[1]=q4.y;
        M[2]=q0.x;  M[3]=q0.y;  M[4]=q0.z;  M[5]=q0.w;
        M[6]=q1.x;  M[7]=q1.y;  M[8]=q1.z;  M[9]=q1.w;
        M[10]=q2.x; M[11]=q2.y; M[12]=q2.z; M[13]=q2.w;
        M[14]=q3.x; M[15]=q3.y; M[16]=q3.z; M[17]=q3.w;
    }
}

// U matrices: base (bs*4+a)*72B, runtime a -> parity unknown, 9x float2 (always 8B-aligned)
__device__ __forceinline__ void load9f2(const float* __restrict__ p, float* M) {
#pragma unroll
    for (int k = 0; k < 9; ++k) {
        float2 e = *(const float2*)(p + 2 * k);
        M[2 * k]     = e.x;
        M[2 * k + 1] = e.y;
    }
}

__global__ __launch_bounds__(256) void lconv_kernel(
    const float* __restrict__ u,
    const float* __restrict__ w,
    const float* __restrict__ wgt,
    float* __restrict__ out)
{
    __shared__ float wT[T_W][N_OUT];        // wT[v][uo] = wgt[uo*37+v]
    __shared__ float exch[256 * SLICE];     // 26.6 KB exchange buffer

    const int tid = threadIdx.x;
    for (int idx = tid; idx < T_W * N_OUT; idx += 256) {
        wT[idx >> 3][idx & 7] = wgt[(idx & 7) * T_W + (idx >> 3)];
    }
    __syncthreads();

    const int gid = blockIdx.x * 256 + tid;

    // fused u -> out passthrough: first 1536 blocks, 3 float4 each (exact cover)
    if (blockIdx.x < COPY_BLOCKS) {
        const float4* __restrict__ u4 = (const float4*)u;
        float4* __restrict__ o4 = (float4*)out;
#pragma unroll
        for (int k = 0; k < 3; ++k) {
            int idx = gid + k * (COPY_BLOCKS * 256);
            o4[idx] = u4[idx];
        }
    }

    const int a  = tid & 3;          // axis (addresses only)
    const int sj = gid >> 2;         // (site, j)
    const int j  = sj % 3;
    const int bs = sj / 3;
    const int x  = bs & (NX - 1);

    // axis geometry: dims (8,8,16,16), strides 2^{11,8,4,0}
    const int sh    = (a == 0) ? 11 : (a == 1) ? 8 : (a == 2) ? 4 : 0;
    const int dmask = (a < 2) ? 7 : 15;
    const int ca    = (x >> sh) & dmask;
    const int xp    = (ca == dmask) ? x - (dmask << sh) : x + (1 << sh);
    const int xm    = (ca == 0)     ? x + (dmask << sh) : x - (1 << sh);
    const int bsp   = bs - x + xp;
    const int bsm   = bs - x + xm;

    float acc[N_OUT][NCOL][2];
#pragma unroll
    for (int uo = 0; uo < N_OUT; ++uo)
#pragma unroll
        for (int i = 0; i < NCOL; ++i) { acc[uo][i][0] = 0.f; acc[uo][i][1] = 0.f; }

    // ---- term 0: this thread handles v = a (all 8 output channels) ----
    {
        const float* __restrict__ wb = w + (size_t)(bs * 4 + a) * MAT;
        float4 lo = *(const float4*)&wT[a][0];
        float4 hi = *(const float4*)&wT[a][4];
        const float cw[8] = {lo.x, lo.y, lo.z, lo.w, hi.x, hi.y, hi.z, hi.w};
#pragma unroll
        for (int i = 0; i < NCOL; ++i) {
            float2 e = *(const float2*)(wb + (i * NCOL + j) * 2);
#pragma unroll
            for (int uo = 0; uo < N_OUT; ++uo) {
                acc[uo][i][0] = fmaf(cw[uo], e.x, acc[uo][i][0]);
                acc[uo][i][1] = fmaf(cw[uo], e.y, acc[uo][i][1]);
            }
        }
    }

    // ---- orientation +1: U = u(x,a); neighbor w at bsp ----
    {
        const float* __restrict__ Up = u + (size_t)(bs * 4 + a) * MAT;
        float U[MAT];
        load9f2(Up, U);
        float vr[3], vi[3];                  // d+ = conj(row j of U)
#pragma unroll
        for (int k = 0; k < 3; ++k) {
            float2 e = *(const float2*)(Up + (j * NCOL + k) * 2);
            vr[k] = e.x;  vi[k] = -e.y;
        }
        const float* __restrict__ wn = w + (size_t)bsp * (N_IN * MAT);
#pragma unroll
        for (int v = 0; v < N_IN; ++v) {
            float W[MAT];
            if ((v & 1) == 0) load_mat18<0>(wn + v * MAT, W);
            else              load_mat18<1>(wn + v * MAT, W);

            float yr[3], yi[3];
#pragma unroll
            for (int i = 0; i < NCOL; ++i) {
                float sr = 0.f, si = 0.f;
#pragma unroll
                for (int k = 0; k < NCOL; ++k) {
                    float wr = W[(i*3+k)*2], wi = W[(i*3+k)*2+1];
                    sr = fmaf(wr, vr[k], sr); sr = fmaf(-wi, vi[k], sr);
                    si = fmaf(wr, vi[k], si); si = fmaf(wi, vr[k], si);
                }
                yr[i] = sr; yi[i] = si;
            }
            float cr[3], ci[3];              // c+ = U * y (rows)
#pragma unroll
            for (int i = 0; i < NCOL; ++i) {
                float sr = 0.f, si = 0.f;
#pragma unroll
                for (int k = 0; k < NCOL; ++k) {
                    float ur = U[(i*3+k)*2], ui = U[(i*3+k)*2+1];
                    sr = fmaf(ur, yr[k], sr); sr = fmaf(-ui, yi[k], sr);
                    si = fmaf(ur, yi[k], si); si = fmaf(ui, yr[k], si);
                }
                cr[i] = sr; ci[i] = si;
            }
            float4 lo = *(const float4*)&wT[(1 + a) * 4 + v][0];
            float4 hi = *(const float4*)&wT[(1 + a) * 4 + v][4];
            const float cw[8] = {lo.x, lo.y, lo.z, lo.w, hi.x, hi.y, hi.z, hi.w};
#pragma unroll
            for (int uo = 0; uo < N_OUT; ++uo)
#pragma unroll
                for (int i = 0; i < NCOL; ++i) {
                    acc[uo][i][0] = fmaf(cw[uo], cr[i], acc[uo][i][0]);
                    acc[uo][i][1] = fmaf(cw[uo], ci[i], acc[uo][i][1]);
                }
        }
    }

    // ---- orientation -1: U = u(x-e_a,a); neighbor w at bsm ----
    {
        const float* __restrict__ Um = u + (size_t)(bsm * 4 + a) * MAT;
        float U[MAT];
        load9f2(Um, U);
        float vr[3], vi[3];                  // d- = column j of U (no conj)
#pragma unroll
        for (int k = 0; k < 3; ++k) {
            float2 e = *(const float2*)(Um + (k * NCOL + j) * 2);
            vr[k] = e.x;  vi[k] = e.y;
        }
        const float* __restrict__ wn = w + (size_t)bsm * (N_IN * MAT);
#pragma unroll
        for (int v = 0; v < N_IN; ++v) {
            float W[MAT];
            if ((v & 1) == 0) load_mat18<0>(wn + v * MAT, W);
            else              load_mat18<1>(wn + v * MAT, W);

            float yr[3], yi[3];
#pragma unroll
            for (int i = 0; i < NCOL; ++i) {
                float sr = 0.f, si = 0.f;
#pragma unroll
                for (int k = 0; k < NCOL; ++k) {
                    float wr = W[(i*3+k)*2], wi = W[(i*3+k)*2+1];
                    sr = fmaf(wr, vr[k], sr); sr = fmaf(-wi, vi[k], sr);
                    si = fmaf(wr, vi[k], si); si = fmaf(wi, vr[k], si);
                }
                yr[i] = sr; yi[i] = si;
            }
            float cr[3], ci[3];              // c- = U^H * y (conj columns)
#pragma unroll
            for (int i = 0; i < NCOL; ++i) {
                float sr = 0.f, si = 0.f;
#pragma unroll
                for (int k = 0; k < NCOL; ++k) {
                    float ur = U[(k*3+i)*2], ui = U[(k*3+i)*2+1];
                    sr = fmaf(ur, yr[k], sr); sr = fmaf(ui, yi[k], sr);
                    si = fmaf(ur, yi[k], si); si = fmaf(-ui, yr[k], si);
                }
                cr[i] = sr; ci[i] = si;
            }
            float4 lo = *(const float4*)&wT[(5 + a) * 4 + v][0];
            float4 hi = *(const float4*)&wT[(5 + a) * 4 + v][4];
            const float cw[8] = {lo.x, lo.y, lo.z, lo.w, hi.x, hi.y, hi.z, hi.w};
#pragma unroll
            for (int uo = 0; uo < N_OUT; ++uo)
#pragma unroll
                for (int i = 0; i < NCOL; ++i) {
                    acc[uo][i][0] = fmaf(cw[uo], cr[i], acc[uo][i][0]);
                    acc[uo][i][1] = fmaf(cw[uo], ci[i], acc[uo][i][1]);
                }
        }
    }

    // ---- reduction over the 4 axis-lanes via LDS, two phases ----
    float* __restrict__ slot = &exch[tid * SLICE];
    const int gslot = tid & ~3;              // first slot of my 4-lane group
    float* __restrict__ obase = out + (size_t)OUT_U + (size_t)bs * (N_OUT * MAT);

    // Phase A: channels 0..3. All lanes ship acc[0..3]; lane a sums+stores channel a.
#pragma unroll
    for (int t = 0; t < 4; ++t)
#pragma unroll
        for (int i = 0; i < NCOL; ++i)
            *(float2*)(slot + t * 6 + i * 2) = make_float2(acc[t][i][0], acc[t][i][1]);
    __syncthreads();
    {
        float s[6] = {0.f, 0.f, 0.f, 0.f, 0.f, 0.f};
#pragma unroll
        for (int l = 0; l < 4; ++l) {
            const float* __restrict__ ps = &exch[(gslot + l) * SLICE + a * 6];
#pragma unroll
            for (int m = 0; m < 3; ++m) {
                float2 e = *(const float2*)(ps + 2 * m);
                s[2 * m]     += e.x;
                s[2 * m + 1] += e.y;
            }
        }
        const float cid = wT[36][a];
#pragma unroll
        for (int i = 0; i < NCOL; ++i) {
            float2 e;
            e.x = s[i * 2] + ((i == j) ? cid : 0.f);
            e.y = s[i * 2 + 1];
            *(float2*)(obase + a * MAT + (i * NCOL + j) * 2) = e;
        }
    }
    __syncthreads();

    // Phase B: channels 4..7. Lane a sums+stores channel 4+a.
#pragma unroll
    for (int t = 0; t < 4; ++t)
#pragma unroll
        for (int i = 0; i < NCOL; ++i)
            *(float2*)(slot + t * 6 + i * 2) = make_float2(acc[4 + t][i][0], acc[4 + t][i][1]);
    __syncthreads();
    {
        float s[6] = {0.f, 0.f, 0.f, 0.f, 0.f, 0.f};
#pragma unroll
        for (int l = 0; l < 4; ++l) {
            const float* __restrict__ ps = &exch[(gslot + l) * SLICE + a * 6];
#pragma unroll
            for (int m = 0; m < 3; ++m) {
                float2 e = *(const float2*)(ps + 2 * m);
                s[2 * m]     += e.x;
                s[2 * m + 1] += e.y;
            }
        }
        const float cid = wT[36][4 + a];
#pragma unroll
        for (int i = 0; i < NCOL; ++i) {
            float2 e;
            e.x = s[i * 2] + ((i == j) ? cid : 0.f);
            e.y = s[i * 2 + 1];
            *(float2*)(obase + (4 + a) * MAT + (i * NCOL + j) * 2) = e;
        }
    }
}

} // namespace

extern "C" void kernel_launch(void* const* d_in, const int* in_sizes, int n_in,
                              void* d_out, int out_size, void* d_ws, size_t ws_size,
                              hipStream_t stream)
{
    const float* u   = (const float*)d_in[0];
    const float* w   = (const float*)d_in[1];
    const float* wgt = (const float*)d_in[2];
    float* out = (float*)d_out;

    dim3 block(256);
    dim3 grid(NTHREADS / 256);   // 3072 blocks, exact cover
    lconv_kernel<<<grid, block, 0, stream>>>(u, w, wgt, out);
}